// Round 3
// baseline (64.376 us; speedup 1.0000x reference)
//
#include <hip/hip_runtime.h>
#include <hip/hip_bf16.h>

#define B_   16
#define L_   256
#define D_   512
#define C_   8
#define P_   12
#define LOUT 244
#define O_   512
#define GM   3904   // 16*244 rows per channel; 61*64 exactly
#define NT   61

typedef __attribute__((ext_vector_type(8))) short bf16x8;
typedef __attribute__((ext_vector_type(4))) float f32x4;

__device__ __forceinline__ unsigned short f2bf(float f) {
    unsigned int u = __float_as_uint(f);
    unsigned int r = (u + 0x7FFFu + ((u >> 16) & 1u)) >> 16;
    return (unsigned short)r;
}

__device__ __forceinline__ void async_copy16(const void* g, void* l) {
    __builtin_amdgcn_global_load_lds(
        (const __attribute__((address_space(1))) unsigned int*)g,
        (__attribute__((address_space(3))) unsigned int*)l, 16, 0, 0);
}

// ---------------------------------------------------------------------------
// wsb convert: Ws f32 -> bf16 (one float4 per thread)
// ---------------------------------------------------------------------------
__global__ __launch_bounds__(256) void ws_convert(const float* __restrict__ Ws,
                                                  unsigned short* __restrict__ wsb) {
    int g = blockIdx.x * 256 + threadIdx.x;   // 524288 float4s
    float4 v = ((const float4*)Ws)[g];
    ushort4 o;
    o.x = f2bf(v.x); o.y = f2bf(v.y); o.z = f2bf(v.z); o.w = f2bf(v.w);
    ((ushort4*)wsb)[g] = o;
}

// ---------------------------------------------------------------------------
// fused: per (c, mt): out[r, o] = sum_d (FIR_c(inp)[r,d]) * Ws[c,o,d] + bias
//   BM=64 (rows r = mt*64..+63), BN=512 (all o), BK=64, 1024 thr = 16 waves.
//   A-tile: FIR computed in-regs, bf16, ds_write_b64, XOR-swizzled.
//   B-tile: global_load_lds x16, linear dest + inverse-swizzled source.
//   Swizzle: chunk' = chunk ^ (row & 7)   (16B chunks, 8 per 128B row)
//   grid 488 = mt*8 + c  ->  XCD (bid%8) == c: wsb_c L2-resident per XCD.
// ---------------------------------------------------------------------------
__global__ __launch_bounds__(1024, 4) void fused(const float* __restrict__ inp,
                                                 const unsigned short* __restrict__ wsb,
                                                 const float* __restrict__ bs,
                                                 const float* __restrict__ Wt,
                                                 const float* __restrict__ bt,
                                                 float* __restrict__ out) {
    __shared__ unsigned short As[64 * 64];    // 8 KB, swizzled
    __shared__ unsigned short Bs[512 * 64];   // 64 KB, swizzled

    int bid = blockIdx.x;
    int c = bid & 7, mt = bid >> 3;
    int row0 = mt * 64;
    int tid = threadIdx.x;
    int lane = tid & 63, wid = tid >> 6;      // 16 waves
    int wm = wid >> 3, wn = wid & 7;          // 2M x 8N -> wave tile 32 x 64

    // FIR weights (uniform -> SGPR)
    float w[P_];
#pragma unroll
    for (int p = 0; p < P_; ++p) w[p] = Wt[c * P_ + p];

    // FIR task: row frow (0..63), cols fcol..fcol+3 of the K-slice
    int frow = tid >> 4;
    int fcol = (tid & 15) * 4;
    int rg = row0 + frow;
    int fb = rg / LOUT, fl = rg % LOUT;       // l+p <= 243+11 = 254 < 256: safe
    const float* fir_base = inp + ((size_t)fb * L_ + fl) * D_ + fcol;
    // swizzled A write index (ushort units): chunk ^= frow&7, keep in-chunk off
    int awr = frow * 64 + (((fcol >> 3) ^ (frow & 7)) << 3) + (fcol & 7);

    const unsigned short* Bb = wsb + (size_t)c * O_ * D_;

    f32x4 acc[2][4];
#pragma unroll
    for (int m = 0; m < 2; ++m)
#pragma unroll
        for (int n = 0; n < 4; ++n)
            acc[m][n] = (f32x4){0.f, 0.f, 0.f, 0.f};

    for (int d0 = 0; d0 < D_; d0 += 64) {
        __syncthreads();

        // ---- stage B: 4096 16B-chunks, 4 per thread, swizzled source ----
#pragma unroll
        for (int h = 0; h < 4; ++h) {
            int q = h * 1024 + tid;
            int brow = q >> 3, cc = q & 7;
            int sc = cc ^ (brow & 7);
            async_copy16(Bb + (size_t)brow * D_ + d0 + sc * 8,
                         (unsigned short*)Bs + (size_t)q * 8);
        }

        // ---- FIR -> A-tile (two 6-deep load batches to bound live VGPRs) --
        float s0 = 0.f, s1 = 0.f, s2 = 0.f, s3 = 0.f;
        {
            float4 v[6];
#pragma unroll
            for (int p = 0; p < 6; ++p)
                v[p] = *(const float4*)(fir_base + (size_t)p * D_ + d0);
#pragma unroll
            for (int p = 0; p < 6; ++p) {
                s0 += w[p] * v[p].x; s1 += w[p] * v[p].y;
                s2 += w[p] * v[p].z; s3 += w[p] * v[p].w;
            }
#pragma unroll
            for (int p = 0; p < 6; ++p)
                v[p] = *(const float4*)(fir_base + (size_t)(p + 6) * D_ + d0);
#pragma unroll
            for (int p = 0; p < 6; ++p) {
                s0 += w[p + 6] * v[p].x; s1 += w[p + 6] * v[p].y;
                s2 += w[p + 6] * v[p].z; s3 += w[p + 6] * v[p].w;
            }
        }
        ushort4 ov;
        ov.x = f2bf(s0); ov.y = f2bf(s1); ov.z = f2bf(s2); ov.w = f2bf(s3);
        *(ushort4*)&As[awr] = ov;

        __syncthreads();   // compiler drains vmcnt+lgkmcnt here

        // ---- MFMA: 2 kk x (2m x 4n) ----
#pragma unroll
        for (int kk = 0; kk < 2; ++kk) {
            int cb = kk * 32 + ((lane >> 4) << 3);   // 8-aligned col
            int cch = cb >> 3;
            bf16x8 af[2], bq[4];
#pragma unroll
            for (int m = 0; m < 2; ++m) {
                int r = wm * 32 + m * 16 + (lane & 15);
                af[m] = *(const bf16x8*)&As[r * 64 + ((cch ^ (r & 7)) << 3)];
            }
#pragma unroll
            for (int n = 0; n < 4; ++n) {
                int o = wn * 64 + n * 16 + (lane & 15);
                bq[n] = *(const bf16x8*)&Bs[o * 64 + ((cch ^ (o & 7)) << 3)];
            }
#pragma unroll
            for (int m = 0; m < 2; ++m)
#pragma unroll
                for (int n = 0; n < 4; ++n)
                    acc[m][n] = __builtin_amdgcn_mfma_f32_16x16x32_bf16(
                        af[m], bq[n], acc[m][n], 0, 0, 0);
        }
    }

    // ---- epilogue ----
    float S = 0.f;
#pragma unroll
    for (int p = 0; p < P_; ++p) S += w[p];
    float btc = bt[c];

#pragma unroll
    for (int m = 0; m < 2; ++m) {
        int rb = row0 + wm * 32 + m * 16 + ((lane >> 4) << 2);
#pragma unroll
        for (int n = 0; n < 4; ++n) {
            int col = wn * 64 + n * 16 + (lane & 15);
            float add = bs[c * O_ + col] * S + btc;
#pragma unroll
            for (int i = 0; i < 4; ++i) {
                int r = rb + i;
                out[((size_t)r * C_ + c) * O_ + col] = acc[m][n][i] + add;
            }
        }
    }
}

// ---------------------------------------------------------------------------
// Fallback (ws too small): slow but correct, no workspace.
// ---------------------------------------------------------------------------
__global__ __launch_bounds__(256) void naive_k(const float* __restrict__ inp,
                                               const float* __restrict__ Ws,
                                               const float* __restrict__ bs,
                                               const float* __restrict__ Wt,
                                               const float* __restrict__ bt,
                                               float* __restrict__ out) {
    __shared__ float tmp[D_];
    int bid = blockIdx.x;
    int c = bid & 7; int r = bid >> 3;
    int l = r % LOUT; int b = r / LOUT;
    int tid = threadIdx.x;

    for (int d = tid; d < D_; d += 256) {
        float s = 0.f;
        for (int p = 0; p < P_; ++p)
            s += Wt[c * P_ + p] * inp[((size_t)b * L_ + l + p) * D_ + d];
        tmp[d] = s;
    }
    __syncthreads();
    float S = 0.f;
    for (int p = 0; p < P_; ++p) S += Wt[c * P_ + p];
    for (int o = tid; o < O_; o += 256) {
        const float* wrow = Ws + ((size_t)c * O_ + o) * D_;
        float s = 0.f;
        for (int d = 0; d < D_; ++d) s += wrow[d] * tmp[d];
        out[(((size_t)b * LOUT + l) * C_ + c) * O_ + o] =
            s + bs[c * O_ + o] * S + bt[c];
    }
}

extern "C" void kernel_launch(void* const* d_in, const int* in_sizes, int n_in,
                              void* d_out, int out_size, void* d_ws, size_t ws_size,
                              hipStream_t stream) {
    const float* inp = (const float*)d_in[0];
    const float* Ws  = (const float*)d_in[1];
    const float* bs  = (const float*)d_in[2];
    const float* Wt  = (const float*)d_in[3];
    const float* bt  = (const float*)d_in[4];
    float* out = (float*)d_out;

    const size_t WSBB = (size_t)C_ * O_ * D_ * 2;   // 4,194,304 bytes

    if (ws_size >= WSBB) {
        unsigned short* wsb = (unsigned short*)d_ws;
        ws_convert<<<2048, 256, 0, stream>>>(Ws, wsb);
        fused<<<NT * C_, 1024, 0, stream>>>(inp, wsb, bs, Wt, bt, out);
    } else {
        naive_k<<<B_ * LOUT * C_, 256, 0, stream>>>(inp, Ws, bs, Wt, bt, out);
    }
}

// Round 4
// 61.668 us; speedup vs baseline: 1.0439x; 1.0439x over previous
//
#include <hip/hip_runtime.h>
#include <hip/hip_bf16.h>

#define B_   16
#define L_   256
#define D_   512
#define C_   8
#define P_   12
#define LOUT 244
#define O_   512
#define GM   3904   // 61*64 exactly
#define BM   64
#define BN   256
#define BK   64
#define NMT  61
#define NNT  2

typedef __attribute__((ext_vector_type(8))) short bf16x8;
typedef __attribute__((ext_vector_type(4))) float f32x4;

__device__ __forceinline__ unsigned short f2bf(float f) {
    unsigned int u = __float_as_uint(f);
    unsigned int r = (u + 0x7FFFu + ((u >> 16) & 1u)) >> 16;
    return (unsigned short)r;
}

__device__ __forceinline__ void async_copy16(const void* g, void* l) {
    __builtin_amdgcn_global_load_lds(
        (const __attribute__((address_space(1))) unsigned int*)g,
        (__attribute__((address_space(3))) unsigned int*)l, 16, 0, 0);
}

// ---------------------------------------------------------------------------
// wsb convert: Ws f32 -> bf16 (one float4 per thread)
// ---------------------------------------------------------------------------
__global__ __launch_bounds__(256) void ws_convert(const float* __restrict__ Ws,
                                                  unsigned short* __restrict__ wsb) {
    int g = blockIdx.x * 256 + threadIdx.x;   // 524288 float4s
    float4 v = ((const float4*)Ws)[g];
    ushort4 o;
    o.x = f2bf(v.x); o.y = f2bf(v.y); o.z = f2bf(v.z); o.w = f2bf(v.w);
    ((ushort4*)wsb)[g] = o;
}

// ---------------------------------------------------------------------------
// fused, 2-phase double-buffered:
//   per (c, mt, nt): out[r, o] = sum_d FIR_c(inp)[r,d] * Ws[c,o,d] + bias
//   BM=64, BN=256, BK=64, 512 thr = 8 waves (2M x 4N), wave tile 32x64.
//   Pipeline per K-step: issue B global_load_lds(t+1) + FIR loads(t+1) ->
//   MFMA(t) -> FIR fma + ds_write(t+1) -> __syncthreads (single drain).
//   LDS 80 KB (2 buf x (A 8K + B 32K)) -> 2 blocks/CU.
//   XOR swizzle (16B chunks ^ row&7): B pre-swizzled at global source
//   (linear dest, rule 21), A swizzled at ds_write; reads un-swizzle.
//   grid 976 = (mt + 61*nt)*8 + c -> channel per XCD, B panel L2-resident.
// ---------------------------------------------------------------------------
__global__ __launch_bounds__(512, 4) void fused(const float* __restrict__ inp,
                                                const unsigned short* __restrict__ wsb,
                                                const float* __restrict__ bs,
                                                const float* __restrict__ Wt,
                                                const float* __restrict__ bt,
                                                float* __restrict__ out) {
    __shared__ unsigned short As0[BM * BK], As1[BM * BK];
    __shared__ unsigned short Bs0[BN * BK], Bs1[BN * BK];

    int bid = blockIdx.x;
    int c  = bid & 7;
    int t2 = bid >> 3;                 // 0..121
    int mt = t2 % NMT, nt = t2 / NMT;
    int row0 = mt * BM;
    int tid = threadIdx.x, lane = tid & 63, wid = tid >> 6;
    int wm = wid >> 2, wn = wid & 3;   // 2 x 4

    // FIR weights: wave-uniform -> SGPRs
    float w[P_];
#pragma unroll
    for (int p = 0; p < P_; ++p) w[p] = Wt[c * P_ + p];

    // FIR task: 4 consecutive rows (lq*4..+3), one d-pair (dp*2, dp*2+1).
    // 244 and 64 are multiples of 4 -> 4-row group never crosses a batch.
    int lq = tid >> 5;                 // 0..15
    int dp = tid & 31;                 // 0..31
    int rg = row0 + lq * 4;
    int fb = rg / LOUT, fl = rg % LOUT;
    const float* fir_base = inp + ((size_t)fb * L_ + fl) * D_ + dp * 2;
    int awr[4];
#pragma unroll
    for (int j = 0; j < 4; ++j) {
        int rj = lq * 4 + j;
        awr[j] = rj * BK + ((((dp >> 2) ^ (rj & 7)) << 3) + ((dp & 3) << 1));
    }

    const unsigned short* Bb = wsb + ((size_t)c * O_ + nt * BN) * D_;

    f32x4 acc[2][4];
#pragma unroll
    for (int m = 0; m < 2; ++m)
#pragma unroll
        for (int n = 0; n < 4; ++n)
            acc[m][n] = (f32x4){0.f, 0.f, 0.f, 0.f};

    unsigned short *Ac = As0, *Bc = Bs0, *An = As1, *Bn = Bs1;

#define STAGE_B(dst, dcol)                                                    \
    _Pragma("unroll")                                                         \
    for (int h = 0; h < 4; ++h) {                                             \
        int q = h * 512 + tid;                                                \
        int brow = q >> 3, cc = q & 7;                                        \
        async_copy16(Bb + (size_t)brow * D_ + (dcol) + ((cc ^ (brow & 7)) << 3), \
                     (dst) + q * 8);                                          \
    }

#define FIR_LOAD(vv, dcol)                                                    \
    _Pragma("unroll")                                                         \
    for (int j = 0; j < 15; ++j)                                              \
        vv[j] = *(const float2*)(fir_base + (size_t)j * D_ + (dcol));

#define FIR_STORE(vv, dst)                                                    \
    _Pragma("unroll")                                                         \
    for (int j = 0; j < 4; ++j) {                                             \
        float sx = 0.f, sy = 0.f;                                             \
        _Pragma("unroll")                                                     \
        for (int p = 0; p < P_; ++p) {                                        \
            sx += w[p] * vv[j + p].x;                                         \
            sy += w[p] * vv[j + p].y;                                         \
        }                                                                     \
        ushort2 ov; ov.x = f2bf(sx); ov.y = f2bf(sy);                         \
        *(ushort2*)&(dst)[awr[j]] = ov;                                       \
    }

#define MFMA_STEP(Asrc, Bsrc)                                                 \
    _Pragma("unroll")                                                         \
    for (int kk = 0; kk < 2; ++kk) {                                          \
        bf16x8 af[2], bq[4];                                                  \
        _Pragma("unroll")                                                     \
        for (int m = 0; m < 2; ++m) {                                         \
            int r = wm * 32 + m * 16 + (lane & 15);                           \
            af[m] = *(const bf16x8*)&(Asrc)[r * BK +                          \
                    (((kk * 4 + (lane >> 4)) ^ (r & 7)) << 3)];               \
        }                                                                     \
        _Pragma("unroll")                                                     \
        for (int n = 0; n < 4; ++n) {                                         \
            int o = wn * 64 + n * 16 + (lane & 15);                           \
            bq[n] = *(const bf16x8*)&(Bsrc)[o * BK +                          \
                    (((kk * 4 + (lane >> 4)) ^ (o & 7)) << 3)];               \
        }                                                                     \
        _Pragma("unroll")                                                     \
        for (int m = 0; m < 2; ++m)                                           \
            _Pragma("unroll")                                                 \
            for (int n = 0; n < 4; ++n)                                       \
                acc[m][n] = __builtin_amdgcn_mfma_f32_16x16x32_bf16(          \
                    af[m], bq[n], acc[m][n], 0, 0, 0);                        \
    }

    // ---- prologue: stage t=0 ----
    {
        STAGE_B(Bc, 0)
        float2 v[15];
        FIR_LOAD(v, 0)
        FIR_STORE(v, Ac)
    }
    __syncthreads();

    // ---- main loop: 7 pipelined steps ----
    for (int t = 0; t < 7; ++t) {
        int dn = (t + 1) * BK;
        STAGE_B(Bn, dn)                 // async into next buffer
        float2 v[15];
        FIR_LOAD(v, dn)                 // issue early; latency hides under MFMA
        MFMA_STEP(Ac, Bc)
        FIR_STORE(v, An)                // waits FIR loads (drains B too), writes A(t+1)
        __syncthreads();
        unsigned short* tp;
        tp = Ac; Ac = An; An = tp;
        tp = Bc; Bc = Bn; Bn = tp;
    }

    // ---- epilogue: last K-step ----
    MFMA_STEP(Ac, Bc)

    // ---- bias + store ----
    float S = 0.f;
#pragma unroll
    for (int p = 0; p < P_; ++p) S += w[p];
    float btc = bt[c];

#pragma unroll
    for (int m = 0; m < 2; ++m) {
        int rb = row0 + wm * 32 + m * 16 + ((lane >> 4) << 2);
#pragma unroll
        for (int n = 0; n < 4; ++n) {
            int gcol = nt * BN + wn * 64 + n * 16 + (lane & 15);
            float add = bs[c * O_ + gcol] * S + btc;
#pragma unroll
            for (int i = 0; i < 4; ++i)
                out[((size_t)(rb + i) * C_ + c) * O_ + gcol] = acc[m][n][i] + add;
        }
    }
#undef STAGE_B
#undef FIR_LOAD
#undef FIR_STORE
#undef MFMA_STEP
}

// ---------------------------------------------------------------------------
// Fallback (ws too small): slow but correct, no workspace.
// ---------------------------------------------------------------------------
__global__ __launch_bounds__(256) void naive_k(const float* __restrict__ inp,
                                               const float* __restrict__ Ws,
                                               const float* __restrict__ bs,
                                               const float* __restrict__ Wt,
                                               const float* __restrict__ bt,
                                               float* __restrict__ out) {
    __shared__ float tmp[D_];
    int bid = blockIdx.x;
    int c = bid & 7; int r = bid >> 3;
    int l = r % LOUT; int b = r / LOUT;
    int tid = threadIdx.x;

    for (int d = tid; d < D_; d += 256) {
        float s = 0.f;
        for (int p = 0; p < P_; ++p)
            s += Wt[c * P_ + p] * inp[((size_t)b * L_ + l + p) * D_ + d];
        tmp[d] = s;
    }
    __syncthreads();
    float S = 0.f;
    for (int p = 0; p < P_; ++p) S += Wt[c * P_ + p];
    for (int o = tid; o < O_; o += 256) {
        const float* wrow = Ws + ((size_t)c * O_ + o) * D_;
        float s = 0.f;
        for (int d = 0; d < D_; ++d) s += wrow[d] * tmp[d];
        out[(((size_t)b * LOUT + l) * C_ + c) * O_ + o] =
            s + bs[c * O_ + o] * S + bt[c];
    }
}

extern "C" void kernel_launch(void* const* d_in, const int* in_sizes, int n_in,
                              void* d_out, int out_size, void* d_ws, size_t ws_size,
                              hipStream_t stream) {
    const float* inp = (const float*)d_in[0];
    const float* Ws  = (const float*)d_in[1];
    const float* bs  = (const float*)d_in[2];
    const float* Wt  = (const float*)d_in[3];
    const float* bt  = (const float*)d_in[4];
    float* out = (float*)d_out;

    const size_t WSBB = (size_t)C_ * O_ * D_ * 2;   // 4,194,304 bytes

    if (ws_size >= WSBB) {
        unsigned short* wsb = (unsigned short*)d_ws;
        ws_convert<<<2048, 256, 0, stream>>>(Ws, wsb);
        fused<<<NMT * NNT * C_, 512, 0, stream>>>(inp, wsb, bs, Wt, bt, out);
    } else {
        naive_k<<<B_ * LOUT * C_, 256, 0, stream>>>(inp, Ws, bs, Wt, bt, out);
    }
}